// Round 1
// baseline (742.059 us; speedup 1.0000x reference)
//
#include <hip/hip_runtime.h>
#include <math.h>

// Problem constants (from reference): B=8, Cin=64, Cout=128, H=W=128, KS=3, N=9
#define BB 8
#define CIN 64
#define COUT 128
#define HH 128
#define WW 128
#define HP 130
#define WP 130
#define NPTS 9
#define KDIM 576   // CIN * 9

// ---------------- zero-fill x_t (border padding) ----------------
__global__ void k_zero(float4* __restrict__ p, int n4) {
    int i = blockIdx.x * 256 + threadIdx.x;
    if (i < n4) p[i] = make_float4(0.f, 0.f, 0.f, 0.f);
}

// ---------------- pad + NCHW->NHWC transpose ----------------
// block = one (b,h) row; grid = B*H = 1024
__global__ __launch_bounds__(256) void k_pad_transpose(
    const float* __restrict__ x, float* __restrict__ x_t) {
    __shared__ float lds[128 * 65];
    int b = blockIdx.x >> 7;
    int h = blockIdx.x & 127;
    for (int e = threadIdx.x; e < 64 * 128; e += 256) {
        int ci = e >> 7, w = e & 127;                         // coalesced read over w
        lds[w * 65 + ci] = x[((b * 64 + ci) * 128 + h) * 128 + w];
    }
    __syncthreads();
    for (int e = threadIdx.x; e < 128 * 64; e += 256) {
        int w = e >> 6, ci = e & 63;                          // coalesced write over ci
        x_t[((b * 130 + h + 1) * 130 + (w + 1)) * 64 + ci] = lds[w * 65 + ci];
    }
}

// ---------------- W_conv (co-major) -> WcT (k-major) ----------------
__global__ void k_wct(const float* __restrict__ Wc, float* __restrict__ WcT) {
    int e = blockIdx.x * 256 + threadIdx.x;
    if (e < KDIM * COUT) {
        int k = e >> 7, co = e & 127;
        WcT[e] = Wc[co * KDIM + k];
    }
}

// ---------------- offset + mask 3x3 convs ----------------
// block handles one (b,h) and 64 w positions; grid = B*H*2 = 2048
__global__ __launch_bounds__(256) void k_offmask(
    const float* __restrict__ x_t, const float* __restrict__ Wp, const float* __restrict__ bp,
    const float* __restrict__ Wm, const float* __restrict__ bm,
    float* __restrict__ offs, float* __restrict__ mask) {
    __shared__ float lds[198 * 65];   // 3 rows x 66 cols x 64 ch, stride 65 (conflict-free)
    int t = blockIdx.x;
    int wt = t & 1, h = (t >> 1) & 127, b = t >> 8;
    int w0 = wt * 64;
    for (int e = threadIdx.x; e < 198 * 64; e += 256) {
        int chunk = e >> 6, ci = e & 63;
        int row = chunk / 66, col = chunk % 66;
        lds[chunk * 65 + ci] = x_t[((b * 130 + h + row) * 130 + (w0 + col)) * 64 + ci];
    }
    __syncthreads();
    for (int e = threadIdx.x; e < 27 * 64; e += 256) {
        int oc = e >> 6, wl = e & 63;
        const float* wrow = (oc < 18) ? (Wp + oc * KDIM) : (Wm + (oc - 18) * KDIM);
        float acc = 0.f;
        for (int ci = 0; ci < 64; ++ci) {
            #pragma unroll
            for (int kx = 0; kx < 3; ++kx) {
                float x0 = lds[(kx * 66 + wl + 0) * 65 + ci];
                float x1 = lds[(kx * 66 + wl + 1) * 65 + ci];
                float x2 = lds[(kx * 66 + wl + 2) * 65 + ci];
                const float* wk = wrow + ci * 9 + kx * 3;
                acc += x0 * wk[0] + x1 * wk[1] + x2 * wk[2];
            }
        }
        int idx = ((b * 128 + h) * 128 + (w0 + wl));
        if (oc < 18) {
            offs[idx * 18 + oc] = acc + bp[oc];
        } else {
            float v = acc + bm[oc - 18];
            mask[idx * 9 + (oc - 18)] = 1.f / (1.f + __expf(-v));
        }
    }
}

// ---------------- main: deformable sample + 576-K dot ----------------
// block = 16 output positions (one b,h, contiguous w); grid = B*H*8 = 8192
__global__ __launch_bounds__(256) void k_main(
    const float* __restrict__ x_t, const float* __restrict__ offs,
    const float* __restrict__ mask, const float* __restrict__ WcT,
    float* __restrict__ out) {
    __shared__ float a_lds[16 * KDIM];   // 36864 B; reused as out-staging after dot
    __shared__ int4   pi[144];           // corner base offsets (lt, rb, lb, rt)
    __shared__ float4 pg4[144];          // bilinear weights * modulation
    int t = blockIdx.x;
    int wt = t & 7, h = (t >> 3) & 127, b = t >> 10;
    int w0 = wt * 16;
    int tid = threadIdx.x;

    if (tid < 144) {
        int pos = tid / 9, n = tid % 9;
        int w = w0 + pos;
        int idx = ((b * 128 + h) * 128 + w);
        float ox = offs[idx * 18 + n];
        float oy = offs[idx * 18 + 9 + n];
        float mv = mask[idx * 9 + n];
        float px = ox + (float)(h + n / 3);       // p0x + pnx = h+1 + (n/3 - 1)
        float py = oy + (float)(w + n % 3);
        float flx = floorf(px), fly = floorf(py);
        float qltx = fminf(fmaxf(flx, 0.f), 129.f);
        float qlty = fminf(fmaxf(fly, 0.f), 129.f);
        float qrbx = fminf(fmaxf(flx + 1.f, 0.f), 129.f);
        float qrby = fminf(fmaxf(fly + 1.f, 0.f), 129.f);
        float pxc = fminf(fmaxf(px, 0.f), 129.f);
        float pyc = fminf(fmaxf(py, 0.f), 129.f);
        float glt = (1.f + qltx - pxc) * (1.f + qlty - pyc);
        float grb = (1.f - qrbx + pxc) * (1.f - qrby + pyc);
        float glb = (1.f + qltx - pxc) * (1.f - qrby + pyc);
        float grt = (1.f - qrbx + pxc) * (1.f + qlty - pyc);
        int ix_lt = (int)qltx, iy_lt = (int)qlty, ix_rb = (int)qrbx, iy_rb = (int)qrby;
        pi[tid] = make_int4((ix_lt * 130 + iy_lt) * 64, (ix_rb * 130 + iy_rb) * 64,
                            (ix_lt * 130 + iy_rb) * 64, (ix_rb * 130 + iy_lt) * 64);
        pg4[tid] = make_float4(glt * mv, grb * mv, glb * mv, grt * mv);
    }
    __syncthreads();

    // gather + blend: wave-uniform point, lane = ci (coalesced 256B reads)
    const float* xb = x_t + (size_t)b * 130 * 130 * 64;
    for (int e = tid; e < 144 * 64; e += 256) {
        int point = e >> 6, ci = e & 63;
        int pos = point / 9, n = point - pos * 9;
        int4 o = pi[point];
        float4 g = pg4[point];
        float v = g.x * xb[o.x + ci] + g.y * xb[o.y + ci] +
                  g.z * xb[o.z + ci] + g.w * xb[o.w + ci];
        a_lds[pos * KDIM + ci * 9 + n] = v;   // stride 9 -> conflict-free
    }
    __syncthreads();

    // dot: thread = (lane=co, pg=pos-group); 2 co x 4 pos per thread
    int lane = tid & 63, pg = tid >> 6;
    float acc[2][4] = {{0.f, 0.f, 0.f, 0.f}, {0.f, 0.f, 0.f, 0.f}};
    const float4* a4 = (const float4*)a_lds;
    for (int k4 = 0; k4 < 144; ++k4) {
        int kk = k4 * 4;
        float w00 = WcT[(kk + 0) * 128 + lane];
        float w01 = WcT[(kk + 1) * 128 + lane];
        float w02 = WcT[(kk + 2) * 128 + lane];
        float w03 = WcT[(kk + 3) * 128 + lane];
        float w10 = WcT[(kk + 0) * 128 + lane + 64];
        float w11 = WcT[(kk + 1) * 128 + lane + 64];
        float w12 = WcT[(kk + 2) * 128 + lane + 64];
        float w13 = WcT[(kk + 3) * 128 + lane + 64];
        #pragma unroll
        for (int p = 0; p < 4; ++p) {
            float4 a = a4[(pg * 4 + p) * 144 + k4];   // broadcast within wave
            acc[0][p] += a.x * w00 + a.y * w01 + a.z * w02 + a.w * w03;
            acc[1][p] += a.x * w10 + a.y * w11 + a.z * w12 + a.w * w13;
        }
    }
    __syncthreads();

    // stage outputs through LDS so global stores are w-contiguous
    float* outst = a_lds;   // [128][17]
    #pragma unroll
    for (int c = 0; c < 2; ++c)
        #pragma unroll
        for (int p = 0; p < 4; ++p)
            outst[(lane + c * 64) * 17 + pg * 4 + p] = acc[c][p];
    __syncthreads();
    for (int e = tid; e < 2048; e += 256) {
        int co = e >> 4, wl = e & 15;
        out[((size_t)(b * 128 + co) * 16384) + h * 128 + w0 + wl] = outst[co * 17 + wl];
    }
}

// ---------------- BN stats: one block per channel ----------------
__global__ __launch_bounds__(256) void k_stats(
    const float* __restrict__ out, float* __restrict__ stats) {
    __shared__ float s1[256], s2[256];
    int co = blockIdx.x;
    float a1 = 0.f, a2 = 0.f;
    for (int b = 0; b < 8; ++b) {
        const float4* p = (const float4*)(out + (size_t)(b * 128 + co) * 16384);
        for (int i = threadIdx.x; i < 4096; i += 256) {
            float4 v = p[i];
            a1 += v.x + v.y + v.z + v.w;
            a2 += v.x * v.x + v.y * v.y + v.z * v.z + v.w * v.w;
        }
    }
    s1[threadIdx.x] = a1; s2[threadIdx.x] = a2;
    __syncthreads();
    for (int s = 128; s > 0; s >>= 1) {
        if (threadIdx.x < (unsigned)s) {
            s1[threadIdx.x] += s1[threadIdx.x + s];
            s2[threadIdx.x] += s2[threadIdx.x + s];
        }
        __syncthreads();
    }
    if (threadIdx.x == 0) { stats[co] = s1[0]; stats[128 + co] = s2[0]; }
}

__global__ void k_finalize(const float* __restrict__ stats, const float* __restrict__ gamma,
                           const float* __restrict__ beta, float* __restrict__ sb) {
    int c = threadIdx.x;
    if (c < 128) {
        const float M = 131072.f;
        float mean = stats[c] / M;
        float var = stats[128 + c] / M - mean * mean;
        float sc = gamma[c] * rsqrtf(var + 1e-5f);
        sb[c] = sc;
        sb[128 + c] = beta[c] - mean * sc;
    }
}

__global__ void k_bnrelu(float* __restrict__ out, const float* __restrict__ sb) {
    int i = blockIdx.x * 256 + threadIdx.x;       // float4 index
    int c = (i >> 12) & 127;
    float4 v = ((float4*)out)[i];
    float sc = sb[c], bi = sb[128 + c];
    v.x = fmaxf(v.x * sc + bi, 0.f);
    v.y = fmaxf(v.y * sc + bi, 0.f);
    v.z = fmaxf(v.z * sc + bi, 0.f);
    v.w = fmaxf(v.w * sc + bi, 0.f);
    ((float4*)out)[i] = v;
}

extern "C" void kernel_launch(void* const* d_in, const int* in_sizes, int n_in,
                              void* d_out, int out_size, void* d_ws, size_t ws_size,
                              hipStream_t stream) {
    const float* x     = (const float*)d_in[0];
    const float* Wp    = (const float*)d_in[1];
    const float* bp    = (const float*)d_in[2];
    const float* Wm    = (const float*)d_in[3];
    const float* bm    = (const float*)d_in[4];
    const float* Wc    = (const float*)d_in[5];
    const float* gamma = (const float*)d_in[6];
    const float* beta  = (const float*)d_in[7];
    float* out = (float*)d_out;
    float* ws  = (float*)d_ws;

    // ws layout (floats)
    float* x_t   = ws;                       // 8*130*130*64 = 8,652,800
    float* WcT   = x_t + 8652800;            // 576*128      = 73,728
    float* offs  = WcT + 73728;              // 8*128*128*18 = 2,359,296
    float* mask  = offs + 2359296;           // 8*128*128*9  = 1,179,648
    float* stats = mask + 1179648;           // 256 (sum, sumsq)
    float* sb    = stats + 256;              // 256 (scale, bias)

    k_zero<<<8450, 256, 0, stream>>>((float4*)x_t, 2163200);
    k_pad_transpose<<<1024, 256, 0, stream>>>(x, x_t);
    k_wct<<<288, 256, 0, stream>>>(Wc, WcT);
    k_offmask<<<2048, 256, 0, stream>>>(x_t, Wp, bp, Wm, bm, offs, mask);
    k_main<<<8192, 256, 0, stream>>>(x_t, offs, mask, WcT, out);
    k_stats<<<128, 256, 0, stream>>>(out, stats);
    k_finalize<<<1, 128, 0, stream>>>(stats, gamma, beta, sb);
    k_bnrelu<<<16384, 256, 0, stream>>>(out, sb);
}

// Round 4
// 683.891 us; speedup vs baseline: 1.0851x; 1.0851x over previous
//
#include <hip/hip_runtime.h>
#include <math.h>

// Problem constants: B=8, Cin=64, Cout=128, H=W=128, KS=3, N=9, K=576
#define KDIM 576
#define ASTRIDE 584   // ushorts per position row in LDS (576 + 8 pad), 1168 B (16B-aligned)

typedef __bf16 v8bf __attribute__((ext_vector_type(8)));
typedef float f32x4 __attribute__((ext_vector_type(4)));

__device__ inline unsigned short f2bf(float f) {
    unsigned int u = __builtin_bit_cast(unsigned int, f);
    u = u + 0x7FFFu + ((u >> 16) & 1u);          // round-to-nearest-even
    return (unsigned short)(u >> 16);
}

// ---------------- zero-fill x_t (border padding) ----------------
__global__ void k_zero(float4* __restrict__ p, int n4) {
    int i = blockIdx.x * 256 + threadIdx.x;
    if (i < n4) p[i] = make_float4(0.f, 0.f, 0.f, 0.f);
}

// ---------------- pad + NCHW->NHWC transpose ----------------
__global__ __launch_bounds__(256) void k_pad_transpose(
    const float* __restrict__ x, float* __restrict__ x_t) {
    __shared__ float lds[128 * 65];
    int b = blockIdx.x >> 7;
    int h = blockIdx.x & 127;
    for (int e = threadIdx.x; e < 64 * 128; e += 256) {
        int ci = e >> 7, w = e & 127;
        lds[w * 65 + ci] = x[((b * 64 + ci) * 128 + h) * 128 + w];
    }
    __syncthreads();
    for (int e = threadIdx.x; e < 128 * 64; e += 256) {
        int w = e >> 6, ci = e & 63;
        x_t[((b * 130 + h + 1) * 130 + (w + 1)) * 64 + ci] = lds[w * 65 + ci];
    }
}

// ---------------- W_conv -> bf16 B-fragments (k' = n*64+ci ordering) ----------------
__global__ void k_wct(const float* __restrict__ Wc, unsigned short* __restrict__ Bfrag) {
    int e = blockIdx.x * 256 + threadIdx.x;
    if (e >= 8 * 18 * 64 * 8) return;
    int j = e & 7, lane = (e >> 3) & 63;
    int kt = (e >> 9) % 18, ct = e / 9216;
    int k = kt * 32 + ((lane >> 4) << 3) + j;     // permuted K index k'
    int co = ct * 16 + (lane & 15);
    int n = k >> 6, ci = k & 63;                  // k' = n*64 + ci
    Bfrag[e] = f2bf(Wc[co * KDIM + ci * 9 + n]);
}

// ---------------- offset + mask 3x3 convs (fp32) ----------------
__global__ __launch_bounds__(256) void k_offmask(
    const float* __restrict__ x_t, const float* __restrict__ Wp, const float* __restrict__ bp,
    const float* __restrict__ Wm, const float* __restrict__ bm,
    float* __restrict__ offs, float* __restrict__ mask) {
    __shared__ float lds[198 * 65];
    int t = blockIdx.x;
    int wt = t & 1, h = (t >> 1) & 127, b = t >> 8;
    int w0 = wt * 64;
    for (int e = threadIdx.x; e < 198 * 64; e += 256) {
        int chunk = e >> 6, ci = e & 63;
        int row = chunk / 66, col = chunk % 66;
        lds[chunk * 65 + ci] = x_t[((b * 130 + h + row) * 130 + (w0 + col)) * 64 + ci];
    }
    __syncthreads();
    for (int e = threadIdx.x; e < 27 * 64; e += 256) {
        int oc = e >> 6, wl = e & 63;
        const float* wrow = (oc < 18) ? (Wp + oc * KDIM) : (Wm + (oc - 18) * KDIM);
        float acc = 0.f;
        for (int ci = 0; ci < 64; ++ci) {
            #pragma unroll
            for (int kx = 0; kx < 3; ++kx) {
                float x0 = lds[(kx * 66 + wl + 0) * 65 + ci];
                float x1 = lds[(kx * 66 + wl + 1) * 65 + ci];
                float x2 = lds[(kx * 66 + wl + 2) * 65 + ci];
                const float* wk = wrow + ci * 9 + kx * 3;
                acc += x0 * wk[0] + x1 * wk[1] + x2 * wk[2];
            }
        }
        int idx = ((b * 128 + h) * 128 + (w0 + wl));
        if (oc < 18) {
            offs[idx * 18 + oc] = acc + bp[oc];
        } else {
            float v = acc + bm[oc - 18];
            mask[idx * 9 + (oc - 18)] = 1.f / (1.f + __expf(-v));
        }
    }
}

// ---------------- main: deformable sample -> dual (MFMA + fp32 check) dot ----------------
__global__ __launch_bounds__(256) void k_main(
    const float* __restrict__ x_t, const float* __restrict__ offs,
    const float* __restrict__ mask, const unsigned short* __restrict__ Bfrag,
    float* __restrict__ out) {
    __shared__ __align__(16) unsigned short a_lds[32 * ASTRIDE];   // 37376 B
    __shared__ int4   pi[288];
    __shared__ float4 pg4[288];

    int blk = blockIdx.x;
    int b  = blk & 7;
    int rem = blk >> 3;
    int h  = rem >> 2;
    int w0 = (rem & 3) * 32;
    int tid = threadIdx.x;

    for (int i = tid; i < 32 * ASTRIDE / 2; i += 256)
        ((unsigned int*)a_lds)[i] = 0u;

    // phase 1
    for (int e = tid; e < 288; e += 256) {
        int pos = e / 9, n = e - pos * 9;
        int w = w0 + pos;
        int idx = ((b * 128 + h) * 128 + w);
        float ox = offs[idx * 18 + n];
        float oy = offs[idx * 18 + 9 + n];
        float mv = mask[idx * 9 + n];
        float px = ox + (float)(h + n / 3);
        float py = oy + (float)(w + n % 3);
        float flx = floorf(px), fly = floorf(py);
        float qltx = fminf(fmaxf(flx, 0.f), 129.f);
        float qlty = fminf(fmaxf(fly, 0.f), 129.f);
        float qrbx = fminf(fmaxf(flx + 1.f, 0.f), 129.f);
        float qrby = fminf(fmaxf(fly + 1.f, 0.f), 129.f);
        float pxc = fminf(fmaxf(px, 0.f), 129.f);
        float pyc = fminf(fmaxf(py, 0.f), 129.f);
        float glt = (1.f + qltx - pxc) * (1.f + qlty - pyc);
        float grb = (1.f - qrbx + pxc) * (1.f - qrby + pyc);
        float glb = (1.f + qltx - pxc) * (1.f - qrby + pyc);
        float grt = (1.f - qrbx + pxc) * (1.f + qlty - pyc);
        int ix_lt = (int)qltx, iy_lt = (int)qlty, ix_rb = (int)qrbx, iy_rb = (int)qrby;
        pi[e] = make_int4((ix_lt * 130 + iy_lt) * 64, (ix_rb * 130 + iy_rb) * 64,
                          (ix_lt * 130 + iy_rb) * 64, (ix_rb * 130 + iy_lt) * 64);
        pg4[e] = make_float4(glt * mv, grb * mv, glb * mv, grt * mv);
    }
    __syncthreads();

    // phase 2: gather+blend, a_lds[pos][k' = n*64 + ci] in bf16
    {
        const float* xb = x_t + (size_t)b * 130 * 130 * 64;
        int ci = tid & 63;
        for (int it = 0; it < 72; ++it) {
            int point = (tid >> 6) + it * 4;
            int pos = (point * 456) >> 12;
            int n = point - pos * 9;
            int4 o = pi[point];
            float4 g = pg4[point];
            float v = g.x * xb[o.x + ci] + g.y * xb[o.y + ci] +
                      g.z * xb[o.z + ci] + g.w * xb[o.w + ci];
            a_lds[pos * ASTRIDE + n * 64 + ci] = f2bf(v);
        }
    }
    __syncthreads();

    // phase 3a: MFMA (round-3 path, under test)
    int wv = tid >> 6, lane = tid & 63;
    int colq = lane & 15, rowq = (lane >> 4) << 2;
    int ab0 = colq * ASTRIDE + ((lane >> 4) << 3);
    int ab1 = ab0 + 16 * ASTRIDE;
    const v8bf* Bf = (const v8bf*)Bfrag;
    f32x4 acc00 = {0.f, 0.f, 0.f, 0.f}, acc01 = acc00, acc10 = acc00, acc11 = acc00;
    #pragma unroll 6
    for (int kt = 0; kt < 18; ++kt) {
        v8bf a0 = *(const v8bf*)&a_lds[ab0 + kt * 32];
        v8bf a1 = *(const v8bf*)&a_lds[ab1 + kt * 32];
        v8bf b0 = Bf[((2 * wv) * 18 + kt) * 64 + lane];
        v8bf b1 = Bf[((2 * wv + 1) * 18 + kt) * 64 + lane];
        acc00 = __builtin_amdgcn_mfma_f32_16x16x32_bf16(a0, b0, acc00, 0, 0, 0);
        acc01 = __builtin_amdgcn_mfma_f32_16x16x32_bf16(a0, b1, acc01, 0, 0, 0);
        acc10 = __builtin_amdgcn_mfma_f32_16x16x32_bf16(a1, b0, acc10, 0, 0, 0);
        acc11 = __builtin_amdgcn_mfma_f32_16x16x32_bf16(a1, b1, acc11, 0, 0, 0);
    }

    // phase 3b: fp32 check dot over the SAME bf16 data, same 16 outputs/thread
    int C0 = wv * 32 + colq;
    float chk[2][8];
    #pragma unroll
    for (int c = 0; c < 2; ++c)
        #pragma unroll
        for (int p = 0; p < 8; ++p) chk[c][p] = 0.f;
    for (int k8 = 0; k8 < 72; ++k8) {
        int kt = k8 >> 2, q = k8 & 3;
        float bfv[2][8];
        #pragma unroll
        for (int c = 0; c < 2; ++c) {
            int co = C0 + c * 16;
            v8bf bv = Bf[((co >> 4) * 18 + kt) * 64 + (co & 15) + (q << 4)];
            #pragma unroll
            for (int j = 0; j < 8; ++j) bfv[c][j] = (float)bv[j];
        }
        #pragma unroll
        for (int p8 = 0; p8 < 8; ++p8) {
            int pos = (p8 < 4) ? (rowq + p8) : (16 + rowq + (p8 - 4));
            v8bf av = *(const v8bf*)&a_lds[pos * ASTRIDE + k8 * 8];
            #pragma unroll
            for (int j = 0; j < 8; ++j) {
                float af = (float)av[j];
                chk[0][p8] += af * bfv[0][j];
                chk[1][p8] += af * bfv[1][j];
            }
        }
    }

    // compare: if MFMA disagrees, burn visible time (timing channel)
    float md = 0.f;
    #pragma unroll
    for (int r = 0; r < 4; ++r) {
        md = fmaxf(md, fabsf(chk[0][r]     - acc00[r]));
        md = fmaxf(md, fabsf(chk[1][r]     - acc01[r]));
        md = fmaxf(md, fabsf(chk[0][4 + r] - acc10[r]));
        md = fmaxf(md, fabsf(chk[1][4 + r] - acc11[r]));
    }
    bool bad = __any(md > 0.05f);
    float spin = md;
    if (bad) {
        for (int i = 0; i < 32768; ++i) spin = fmaf(spin, 1.0000001f, 1e-9f);
    }
    __syncthreads();

    // epilogue: write the fp32 check values (guaranteed-good if staging is good)
    float* outst = (float*)a_lds;                     // [128 co][33]
    #pragma unroll
    for (int r = 0; r < 4; ++r) {
        outst[C0 * 33 + (rowq + r)]               = chk[0][r];
        outst[(C0 + 16) * 33 + (rowq + r)]        = chk[1][r];
        outst[C0 * 33 + (16 + rowq + r)]          = chk[0][4 + r];
        outst[(C0 + 16) * 33 + (16 + rowq + r)]   = chk[1][4 + r];
    }
    if (bad) outst[C0 * 33 + 32] = spin;   // never-read pad column; defeats DCE of the spin
    __syncthreads();
    for (int e = tid; e < 4096; e += 256) {
        int co = e >> 5, wl = e & 31;
        out[((size_t)(b * 128 + co) * 16384) + h * 128 + w0 + wl] = outst[co * 33 + wl];
    }
}

// ---------------- BN stats: one block per (b, co) ----------------
__global__ __launch_bounds__(256) void k_stats(
    const float* __restrict__ out, float* __restrict__ partial) {
    __shared__ float s1[256], s2[256];
    int blk = blockIdx.x;
    const float4* p = (const float4*)(out + (size_t)blk * 16384);
    float a1 = 0.f, a2 = 0.f;
    for (int i = threadIdx.x; i < 4096; i += 256) {
        float4 v = p[i];
        a1 += v.x + v.y + v.z + v.w;
        a2 += v.x * v.x + v.y * v.y + v.z * v.z + v.w * v.w;
    }
    s1[threadIdx.x] = a1; s2[threadIdx.x] = a2;
    __syncthreads();
    for (int s = 128; s > 0; s >>= 1) {
        if (threadIdx.x < (unsigned)s) {
            s1[threadIdx.x] += s1[threadIdx.x + s];
            s2[threadIdx.x] += s2[threadIdx.x + s];
        }
        __syncthreads();
    }
    if (threadIdx.x == 0) { partial[blk] = s1[0]; partial[1024 + blk] = s2[0]; }
}

__global__ void k_finalize(const float* __restrict__ partial, const float* __restrict__ gamma,
                           const float* __restrict__ beta, float* __restrict__ sb) {
    int c = threadIdx.x;
    if (c < 128) {
        float s1 = 0.f, s2 = 0.f;
        for (int b = 0; b < 8; ++b) {
            s1 += partial[b * 128 + c];
            s2 += partial[1024 + b * 128 + c];
        }
        const float M = 131072.f;
        float mean = s1 / M;
        float var = fmaxf(s2 / M - mean * mean, 0.f);
        float sc = gamma[c] * rsqrtf(var + 1e-5f);
        sb[c] = sc;
        sb[128 + c] = beta[c] - mean * sc;
    }
}

__global__ void k_bnrelu(float* __restrict__ out, const float* __restrict__ sb) {
    int i = blockIdx.x * 256 + threadIdx.x;
    int c = (i >> 12) & 127;
    float4 v = ((float4*)out)[i];
    float sc = sb[c], bi = sb[128 + c];
    v.x = fmaxf(v.x * sc + bi, 0.f);
    v.y = fmaxf(v.y * sc + bi, 0.f);
    v.z = fmaxf(v.z * sc + bi, 0.f);
    v.w = fmaxf(v.w * sc + bi, 0.f);
    ((float4*)out)[i] = v;
}

extern "C" void kernel_launch(void* const* d_in, const int* in_sizes, int n_in,
                              void* d_out, int out_size, void* d_ws, size_t ws_size,
                              hipStream_t stream) {
    const float* x     = (const float*)d_in[0];
    const float* Wp    = (const float*)d_in[1];
    const float* bp    = (const float*)d_in[2];
    const float* Wm    = (const float*)d_in[3];
    const float* bm    = (const float*)d_in[4];
    const float* Wc    = (const float*)d_in[5];
    const float* gamma = (const float*)d_in[6];
    const float* beta  = (const float*)d_in[7];
    float* out = (float*)d_out;
    float* ws  = (float*)d_ws;

    float* x_t            = ws;                                  // 8,652,800 f
    unsigned short* Bfrag = (unsigned short*)(x_t + 8652800);    // 73,728 u16 = 36,864 f
    float* offs    = x_t + 8652800 + 36864;                      // 2,359,296 f
    float* mask    = offs + 2359296;                             // 1,179,648 f
    float* partial = mask + 1179648;                             // 2048 f
    float* sb      = partial + 2048;                             // 256 f

    k_zero<<<8450, 256, 0, stream>>>((float4*)x_t, 2163200);
    k_pad_transpose<<<1024, 256, 0, stream>>>(x, x_t);
    k_wct<<<288, 256, 0, stream>>>(Wc, Bfrag);
    k_offmask<<<2048, 256, 0, stream>>>(x_t, Wp, bp, Wm, bm, offs, mask);
    k_main<<<4096, 256, 0, stream>>>(x_t, offs, mask, Bfrag, out);
    k_stats<<<1024, 256, 0, stream>>>(out, partial);
    k_finalize<<<1, 128, 0, stream>>>(partial, gamma, beta, sb);
    k_bnrelu<<<16384, 256, 0, stream>>>(out, sb);
}

// Round 7
// 681.895 us; speedup vs baseline: 1.0882x; 1.0029x over previous
//
#include <hip/hip_runtime.h>
#include <math.h>

// Problem constants: B=8, Cin=64, Cout=128, H=W=128, KS=3, N=9, K=576
#define KDIM 576
#define ASTRIDE 584   // ushorts per position row in LDS (576 + 8 pad), 1168 B (16B-aligned)

typedef __bf16 v8bf __attribute__((ext_vector_type(8)));
typedef float f32x4 __attribute__((ext_vector_type(4)));

__device__ inline unsigned short f2bf(float f) {
    unsigned int u = __builtin_bit_cast(unsigned int, f);
    u = u + 0x7FFFu + ((u >> 16) & 1u);          // round-to-nearest-even
    return (unsigned short)(u >> 16);
}

// ---------------- zero-fill x_t (border padding) ----------------
__global__ void k_zero(float4* __restrict__ p, int n4) {
    int i = blockIdx.x * 256 + threadIdx.x;
    if (i < n4) p[i] = make_float4(0.f, 0.f, 0.f, 0.f);
}

// ---------------- pad + NCHW->NHWC transpose ----------------
__global__ __launch_bounds__(256) void k_pad_transpose(
    const float* __restrict__ x, float* __restrict__ x_t) {
    __shared__ float lds[128 * 65];
    int b = blockIdx.x >> 7;
    int h = blockIdx.x & 127;
    for (int e = threadIdx.x; e < 64 * 128; e += 256) {
        int ci = e >> 7, w = e & 127;
        lds[w * 65 + ci] = x[((b * 64 + ci) * 128 + h) * 128 + w];
    }
    __syncthreads();
    for (int e = threadIdx.x; e < 128 * 64; e += 256) {
        int w = e >> 6, ci = e & 63;
        x_t[((b * 130 + h + 1) * 130 + (w + 1)) * 64 + ci] = lds[w * 65 + ci];
    }
}

// ---------------- W_conv -> bf16 B-fragments (k' = n*64+ci ordering) ----------------
__global__ void k_wct(const float* __restrict__ Wc, unsigned short* __restrict__ Bfrag) {
    int e = blockIdx.x * 256 + threadIdx.x;
    if (e >= 8 * 18 * 64 * 8) return;
    int j = e & 7, lane = (e >> 3) & 63;
    int kt = (e >> 9) % 18, ct = e / 9216;
    int k = kt * 32 + ((lane >> 4) << 3) + j;     // permuted K index k'
    int co = ct * 16 + (lane & 15);
    int n = k >> 6, ci = k & 63;                  // k' = n*64 + ci
    Bfrag[e] = f2bf(Wc[co * KDIM + ci * 9 + n]);
}

// ---------------- offset + mask 3x3 convs (fp32) ----------------
__global__ __launch_bounds__(256) void k_offmask(
    const float* __restrict__ x_t, const float* __restrict__ Wp, const float* __restrict__ bp,
    const float* __restrict__ Wm, const float* __restrict__ bm,
    float* __restrict__ offs, float* __restrict__ mask) {
    __shared__ float lds[198 * 65];
    int t = blockIdx.x;
    int wt = t & 1, h = (t >> 1) & 127, b = t >> 8;
    int w0 = wt * 64;
    for (int e = threadIdx.x; e < 198 * 64; e += 256) {
        int chunk = e >> 6, ci = e & 63;
        int row = chunk / 66, col = chunk % 66;
        lds[chunk * 65 + ci] = x_t[((b * 130 + h + row) * 130 + (w0 + col)) * 64 + ci];
    }
    __syncthreads();
    for (int e = threadIdx.x; e < 27 * 64; e += 256) {
        int oc = e >> 6, wl = e & 63;
        const float* wrow = (oc < 18) ? (Wp + oc * KDIM) : (Wm + (oc - 18) * KDIM);
        float acc = 0.f;
        for (int ci = 0; ci < 64; ++ci) {
            #pragma unroll
            for (int kx = 0; kx < 3; ++kx) {
                float x0 = lds[(kx * 66 + wl + 0) * 65 + ci];
                float x1 = lds[(kx * 66 + wl + 1) * 65 + ci];
                float x2 = lds[(kx * 66 + wl + 2) * 65 + ci];
                const float* wk = wrow + ci * 9 + kx * 3;
                acc += x0 * wk[0] + x1 * wk[1] + x2 * wk[2];
            }
        }
        int idx = ((b * 128 + h) * 128 + (w0 + wl));
        if (oc < 18) {
            offs[idx * 18 + oc] = acc + bp[oc];
        } else {
            float v = acc + bm[oc - 18];
            mask[idx * 9 + (oc - 18)] = 1.f / (1.f + __expf(-v));
        }
    }
}

// ---------------- main: deformable sample -> dual (MFMA + fp32 check) dot ----------------
// R4-identical machinery; mismatch now triggers a BLOCK-WIDE 2^19 dependent-FMA spin
// (~0.9 ms/block) so any MFMA-vs-fp32 disagreement is unmistakable in dur_us.
__global__ __launch_bounds__(256) void k_main(
    const float* __restrict__ x_t, const float* __restrict__ offs,
    const float* __restrict__ mask, const unsigned short* __restrict__ Bfrag,
    float* __restrict__ out) {
    __shared__ __align__(16) unsigned short a_lds[32 * ASTRIDE];   // 37376 B
    __shared__ int4   pi[288];
    __shared__ float4 pg4[288];
    __shared__ int    bad_s;

    int blk = blockIdx.x;
    int b  = blk & 7;
    int rem = blk >> 3;
    int h  = rem >> 2;
    int w0 = (rem & 3) * 32;
    int tid = threadIdx.x;

    if (tid == 0) bad_s = 0;
    for (int i = tid; i < 32 * ASTRIDE / 2; i += 256)
        ((unsigned int*)a_lds)[i] = 0u;

    // phase 1
    for (int e = tid; e < 288; e += 256) {
        int pos = e / 9, n = e - pos * 9;
        int w = w0 + pos;
        int idx = ((b * 128 + h) * 128 + w);
        float ox = offs[idx * 18 + n];
        float oy = offs[idx * 18 + 9 + n];
        float mv = mask[idx * 9 + n];
        float px = ox + (float)(h + n / 3);
        float py = oy + (float)(w + n % 3);
        float flx = floorf(px), fly = floorf(py);
        float qltx = fminf(fmaxf(flx, 0.f), 129.f);
        float qlty = fminf(fmaxf(fly, 0.f), 129.f);
        float qrbx = fminf(fmaxf(flx + 1.f, 0.f), 129.f);
        float qrby = fminf(fmaxf(fly + 1.f, 0.f), 129.f);
        float pxc = fminf(fmaxf(px, 0.f), 129.f);
        float pyc = fminf(fmaxf(py, 0.f), 129.f);
        float glt = (1.f + qltx - pxc) * (1.f + qlty - pyc);
        float grb = (1.f - qrbx + pxc) * (1.f - qrby + pyc);
        float glb = (1.f + qltx - pxc) * (1.f - qrby + pyc);
        float grt = (1.f - qrbx + pxc) * (1.f + qlty - pyc);
        int ix_lt = (int)qltx, iy_lt = (int)qlty, ix_rb = (int)qrbx, iy_rb = (int)qrby;
        pi[e] = make_int4((ix_lt * 130 + iy_lt) * 64, (ix_rb * 130 + iy_rb) * 64,
                          (ix_lt * 130 + iy_rb) * 64, (ix_rb * 130 + iy_lt) * 64);
        pg4[e] = make_float4(glt * mv, grb * mv, glb * mv, grt * mv);
    }
    __syncthreads();

    // phase 2: gather+blend, a_lds[pos][k' = n*64 + ci] in bf16
    {
        const float* xb = x_t + (size_t)b * 130 * 130 * 64;
        int ci = tid & 63;
        for (int it = 0; it < 72; ++it) {
            int point = (tid >> 6) + it * 4;
            int pos = (point * 456) >> 12;
            int n = point - pos * 9;
            int4 o = pi[point];
            float4 g = pg4[point];
            float v = g.x * xb[o.x + ci] + g.y * xb[o.y + ci] +
                      g.z * xb[o.z + ci] + g.w * xb[o.w + ci];
            a_lds[pos * ASTRIDE + n * 64 + ci] = f2bf(v);
        }
    }
    __syncthreads();

    // phase 3a: MFMA (under test)
    int wv = tid >> 6, lane = tid & 63;
    int colq = lane & 15, rowq = (lane >> 4) << 2;
    int ab0 = colq * ASTRIDE + ((lane >> 4) << 3);
    int ab1 = ab0 + 16 * ASTRIDE;
    const v8bf* Bf = (const v8bf*)Bfrag;
    f32x4 acc00 = {0.f, 0.f, 0.f, 0.f}, acc01 = acc00, acc10 = acc00, acc11 = acc00;
    #pragma unroll 6
    for (int kt = 0; kt < 18; ++kt) {
        v8bf a0 = *(const v8bf*)&a_lds[ab0 + kt * 32];
        v8bf a1 = *(const v8bf*)&a_lds[ab1 + kt * 32];
        v8bf b0 = Bf[((2 * wv) * 18 + kt) * 64 + lane];
        v8bf b1 = Bf[((2 * wv + 1) * 18 + kt) * 64 + lane];
        acc00 = __builtin_amdgcn_mfma_f32_16x16x32_bf16(a0, b0, acc00, 0, 0, 0);
        acc01 = __builtin_amdgcn_mfma_f32_16x16x32_bf16(a0, b1, acc01, 0, 0, 0);
        acc10 = __builtin_amdgcn_mfma_f32_16x16x32_bf16(a1, b0, acc10, 0, 0, 0);
        acc11 = __builtin_amdgcn_mfma_f32_16x16x32_bf16(a1, b1, acc11, 0, 0, 0);
    }

    // phase 3b: fp32 check dot over the SAME bf16 data, same 16 outputs/thread
    int C0 = wv * 32 + colq;
    float chk[2][8];
    #pragma unroll
    for (int c = 0; c < 2; ++c)
        #pragma unroll
        for (int p = 0; p < 8; ++p) chk[c][p] = 0.f;
    for (int k8 = 0; k8 < 72; ++k8) {
        int kt = k8 >> 2, q = k8 & 3;
        float bfv[2][8];
        #pragma unroll
        for (int c = 0; c < 2; ++c) {
            int co = C0 + c * 16;
            v8bf bv = Bf[((co >> 4) * 18 + kt) * 64 + (co & 15) + (q << 4)];
            #pragma unroll
            for (int j = 0; j < 8; ++j) bfv[c][j] = (float)bv[j];
        }
        #pragma unroll
        for (int p8 = 0; p8 < 8; ++p8) {
            int pos = (p8 < 4) ? (rowq + p8) : (16 + rowq + (p8 - 4));
            v8bf av = *(const v8bf*)&a_lds[pos * ASTRIDE + k8 * 8];
            #pragma unroll
            for (int j = 0; j < 8; ++j) {
                float af = (float)av[j];
                chk[0][p8] += af * bfv[0][j];
                chk[1][p8] += af * bfv[1][j];
            }
        }
    }

    // compare: ANY mismatch in the block -> whole block burns ~0.9 ms
    float md = 0.f;
    #pragma unroll
    for (int r = 0; r < 4; ++r) {
        md = fmaxf(md, fabsf(chk[0][r]     - acc00[r]));
        md = fmaxf(md, fabsf(chk[1][r]     - acc01[r]));
        md = fmaxf(md, fabsf(chk[0][4 + r] - acc10[r]));
        md = fmaxf(md, fabsf(chk[1][4 + r] - acc11[r]));
    }
    if (md > 0.05f) bad_s = 1;
    __syncthreads();          // also orders a_lds reads before outst overwrite

    float* outst = (float*)a_lds;                     // [128 co][33]
    if (bad_s) {
        float spin = md + 1.f;
        for (int i = 0; i < (1 << 19); ++i) spin = fmaf(spin, 1.0000001f, 1e-9f);
        outst[C0 * 33 + 32] = spin;   // never-read pad column; defeats DCE
    }

    // epilogue: write the fp32 check values (known-good path, R4-passed)
    #pragma unroll
    for (int r = 0; r < 4; ++r) {
        outst[C0 * 33 + (rowq + r)]               = chk[0][r];
        outst[(C0 + 16) * 33 + (rowq + r)]        = chk[1][r];
        outst[C0 * 33 + (16 + rowq + r)]          = chk[0][4 + r];
        outst[(C0 + 16) * 33 + (16 + rowq + r)]   = chk[1][4 + r];
    }
    __syncthreads();
    for (int e = tid; e < 4096; e += 256) {
        int co = e >> 5, wl = e & 31;
        out[((size_t)(b * 128 + co) * 16384) + h * 128 + w0 + wl] = outst[co * 33 + wl];
    }
}

// ---------------- BN stats: one block per (b, co) ----------------
__global__ __launch_bounds__(256) void k_stats(
    const float* __restrict__ out, float* __restrict__ partial) {
    __shared__ float s1[256], s2[256];
    int blk = blockIdx.x;
    const float4* p = (const float4*)(out + (size_t)blk * 16384);
    float a1 = 0.f, a2 = 0.f;
    for (int i = threadIdx.x; i < 4096; i += 256) {
        float4 v = p[i];
        a1 += v.x + v.y + v.z + v.w;
        a2 += v.x * v.x + v.y * v.y + v.z * v.z + v.w * v.w;
    }
    s1[threadIdx.x] = a1; s2[threadIdx.x] = a2;
    __syncthreads();
    for (int s = 128; s > 0; s >>= 1) {
        if (threadIdx.x < (unsigned)s) {
            s1[threadIdx.x] += s1[threadIdx.x + s];
            s2[threadIdx.x] += s2[threadIdx.x + s];
        }
        __syncthreads();
    }
    if (threadIdx.x == 0) { partial[blk] = s1[0]; partial[1024 + blk] = s2[0]; }
}

__global__ void k_finalize(const float* __restrict__ partial, const float* __restrict__ gamma,
                           const float* __restrict__ beta, float* __restrict__ sb) {
    int c = threadIdx.x;
    if (c < 128) {
        float s1 = 0.f, s2 = 0.f;
        for (int b = 0; b < 8; ++b) {
            s1 += partial[b * 128 + c];
            s2 += partial[1024 + b * 128 + c];
        }
        const float M = 131072.f;
        float mean = s1 / M;
        float var = fmaxf(s2 / M - mean * mean, 0.f);
        float sc = gamma[c] * rsqrtf(var + 1e-5f);
        sb[c] = sc;
        sb[128 + c] = beta[c] - mean * sc;
    }
}

__global__ void k_bnrelu(float* __restrict__ out, const float* __restrict__ sb) {
    int i = blockIdx.x * 256 + threadIdx.x;
    int c = (i >> 12) & 127;
    float4 v = ((float4*)out)[i];
    float sc = sb[c], bi = sb[128 + c];
    v.x = fmaxf(v.x * sc + bi, 0.f);
    v.y = fmaxf(v.y * sc + bi, 0.f);
    v.z = fmaxf(v.z * sc + bi, 0.f);
    v.w = fmaxf(v.w * sc + bi, 0.f);
    ((float4*)out)[i] = v;
}

extern "C" void kernel_launch(void* const* d_in, const int* in_sizes, int n_in,
                              void* d_out, int out_size, void* d_ws, size_t ws_size,
                              hipStream_t stream) {
    const float* x     = (const float*)d_in[0];
    const float* Wp    = (const float*)d_in[1];
    const float* bp    = (const float*)d_in[2];
    const float* Wm    = (const float*)d_in[3];
    const float* bm    = (const float*)d_in[4];
    const float* Wc    = (const float*)d_in[5];
    const float* gamma = (const float*)d_in[6];
    const float* beta  = (const float*)d_in[7];
    float* out = (float*)d_out;
    float* ws  = (float*)d_ws;

    float* x_t            = ws;                                  // 8,652,800 f
    unsigned short* Bfrag = (unsigned short*)(x_t + 8652800);    // 73,728 u16 = 36,864 f
    float* offs    = x_t + 8652800 + 36864;                      // 2,359,296 f
    float* mask    = offs + 2359296;                             // 1,179,648 f
    float* partial = mask + 1179648;                             // 2048 f
    float* sb      = partial + 2048;                             // 256 f

    k_zero<<<8450, 256, 0, stream>>>((float4*)x_t, 2163200);
    k_pad_transpose<<<1024, 256, 0, stream>>>(x, x_t);
    k_wct<<<288, 256, 0, stream>>>(Wc, Bfrag);
    k_offmask<<<2048, 256, 0, stream>>>(x_t, Wp, bp, Wm, bm, offs, mask);
    k_main<<<4096, 256, 0, stream>>>(x_t, offs, mask, Bfrag, out);
    k_stats<<<1024, 256, 0, stream>>>(out, partial);
    k_finalize<<<1, 128, 0, stream>>>(partial, gamma, beta, sb);
    k_bnrelu<<<16384, 256, 0, stream>>>(out, sb);
}